// Round 1
// baseline (8773.419 us; speedup 1.0000x reference)
//
#include <hip/hip_runtime.h>
#include <math.h>

#define NXD 256
#define NYD 256
#define NZD 64
#define NCELL (NXD*NYD)

// ---------------- weight transpose: w(k, ci, co) -> wt(k, co, ci) ----------------
template<int CIN>
__global__ __launch_bounds__(256) void transpose_w_k(const float* __restrict__ w,
                                                     float* __restrict__ wt) {
    int k = blockIdx.x;
    for (int idx = threadIdx.x; idx < CIN * 64; idx += 256) {
        int ci = idx % CIN;
        int co = idx / CIN;
        wt[((size_t)k * 64 + co) * CIN + ci] = w[((size_t)k * CIN + ci) * 64 + co];
    }
}

// ---------------- submanifold sparse conv: one wave (64 lanes=c_out) per point ---
template<int CIN, bool RELU>
__global__ __launch_bounds__(256) void subm_conv_k(const float* __restrict__ feats,
        const int* __restrict__ indices, const int* __restrict__ table,
        const float* __restrict__ wt, const float* __restrict__ bias,
        float* __restrict__ out, int M) {
    int p = blockIdx.x * 4 + (threadIdx.x >> 6);
    if (p >= M) return;
    int c = threadIdx.x & 63;
    int x = indices[p * 4 + 1];
    int y = indices[p * 4 + 2];
    int z = indices[p * 4 + 3];
    float acc = bias[c];
    #pragma unroll 1
    for (int k = 0; k < 27; ++k) {
        int dx = k / 9 - 1, dy = (k / 3) % 3 - 1, dz = k % 3 - 1;
        int nx = x + dx, ny = y + dy, nz = z + dz;
        bool valid = (nx >= 0) & (nx < NXD) & (ny >= 0) & (ny < NYD) & (nz >= 0) & (nz < NZD);
        int row = 0;
        if (valid) row = table[(nx * NYD + ny) * NZD + nz];   // wave-uniform
        if (row > 0) {
            const float4* f4 = reinterpret_cast<const float4*>(feats + (size_t)(row - 1) * CIN);
            const float4* w4 = reinterpret_cast<const float4*>(wt + ((size_t)k * 64 + c) * CIN);
            #pragma unroll
            for (int j = 0; j < CIN / 4; ++j) {
                float4 a = f4[j];
                float4 b = w4[j];
                acc = fmaf(a.x, b.x, acc);
                acc = fmaf(a.y, b.y, acc);
                acc = fmaf(a.z, b.z, acc);
                acc = fmaf(a.w, b.w, acc);
            }
        }
    }
    out[(size_t)p * 64 + c] = RELU ? fmaxf(acc, 0.f) : acc;
}

// ---------------- BEV segment max: one wave per (x,y) cell; lane = z then c -----
__global__ __launch_bounds__(256) void bev_max_k(const float* __restrict__ h,
        const int* __restrict__ table, float* __restrict__ bev) {
    int cell = blockIdx.x * 4 + (threadIdx.x >> 6);
    int lane = threadIdx.x & 63;
    int r = table[cell * 64 + lane];          // z = lane (NZ==64)
    float acc = -INFINITY;
    #pragma unroll 1
    for (int z = 0; z < 64; ++z) {
        int row = __shfl(r, z, 64);           // wave-uniform
        if (row > 0) acc = fmaxf(acc, h[(size_t)(row - 1) * 64 + lane]);
    }
    bev[(size_t)lane * NCELL + cell] = (acc == -INFINITY) ? 0.f : acc;
}

// ---------------- dense 5x5 conv, NCHW, pad 2; 16x16 tile per block -------------
template<int CIN, int COB, bool RELU>
__global__ __launch_bounds__(256) void conv5_k(const float* __restrict__ in,
        const float* __restrict__ w, const float* __restrict__ bias,
        float* __restrict__ out) {
    __shared__ float tile[20][20];
    int tid = threadIdx.x;
    int tx = tid & 15, ty = tid >> 4;
    int gx0 = blockIdx.x * 16 - 2, gy0 = blockIdx.y * 16 - 2;
    int co_base = blockIdx.z * COB;
    float acc[COB];
    #pragma unroll
    for (int i = 0; i < COB; ++i) acc[i] = bias[co_base + i];

    #pragma unroll 1
    for (int ci = 0; ci < CIN; ++ci) {
        __syncthreads();
        for (int idx = tid; idx < 400; idx += 256) {
            int r = idx / 20, cc = idx % 20;
            int sy = gy0 + r, sx = gx0 + cc;
            float v = 0.f;
            if (sy >= 0 && sy < NXD && sx >= 0 && sx < NYD)
                v = in[(size_t)ci * NCELL + sy * NYD + sx];
            tile[r][cc] = v;
        }
        __syncthreads();
        const float* wrow = w + ((size_t)co_base * CIN + ci) * 25;  // uniform -> s_load
        #pragma unroll
        for (int dy = 0; dy < 5; ++dy)
        #pragma unroll
        for (int dx = 0; dx < 5; ++dx) {
            float iv = tile[ty + dy][tx + dx];
            #pragma unroll
            for (int co = 0; co < COB; ++co)
                acc[co] = fmaf(iv, wrow[(size_t)co * CIN * 25 + dy * 5 + dx], acc[co]);
        }
    }
    int gy = gy0 + 2 + ty, gx = gx0 + 2 + tx;
    #pragma unroll
    for (int co = 0; co < COB; ++co) {
        float v = acc[co];
        if (RELU) v = fmaxf(v, 0.f);
        out[(size_t)(co_base + co) * NCELL + gy * NYD + gx] = v;
    }
}

// ---------------- pointwise 64->64 + residual add + relu ------------------------
__global__ __launch_bounds__(256) void pw_add_relu_k(const float* __restrict__ x,
        const float* __restrict__ pw, const float* __restrict__ pb,
        const float* __restrict__ h2, float* __restrict__ out) {
    int pix = blockIdx.x * 256 + threadIdx.x;
    int co = blockIdx.y;
    float acc = pb[co] + h2[(size_t)co * NCELL + pix];
    const float* wr = pw + (size_t)co * 64;
    #pragma unroll 8
    for (int ci = 0; ci < 64; ++ci)
        acc = fmaf(x[(size_t)ci * NCELL + pix], wr[ci], acc);
    out[(size_t)co * NCELL + pix] = fmaxf(acc, 0.f);
}

// ---------------- final pointwise 64->3 + residual + relu + NHWC write ----------
__global__ __launch_bounds__(256) void pw_final_k(const float* __restrict__ x,
        const float* __restrict__ pw, const float* __restrict__ pb,
        const float* __restrict__ h2, float* __restrict__ out) {
    int pix = blockIdx.x * 256 + threadIdx.x;
    float acc[3];
    #pragma unroll
    for (int co = 0; co < 3; ++co) acc[co] = pb[co] + h2[(size_t)co * NCELL + pix];
    #pragma unroll 4
    for (int ci = 0; ci < 64; ++ci) {
        float v = x[(size_t)ci * NCELL + pix];
        #pragma unroll
        for (int co = 0; co < 3; ++co) acc[co] = fmaf(v, pw[co * 64 + ci], acc[co]);
    }
    #pragma unroll
    for (int co = 0; co < 3; ++co) out[(size_t)pix * 3 + co] = fmaxf(acc[co], 0.f);
}

extern "C" void kernel_launch(void* const* d_in, const int* in_sizes, int n_in,
                              void* d_out, int out_size, void* d_ws, size_t ws_size,
                              hipStream_t stream) {
    const float* features = (const float*)d_in[0];
    const float* w1   = (const float*)d_in[1];
    const float* b1   = (const float*)d_in[2];
    const float* w2   = (const float*)d_in[3];
    const float* b2   = (const float*)d_in[4];
    const float* w3   = (const float*)d_in[5];
    const float* b3   = (const float*)d_in[6];
    const float* cw11 = (const float*)d_in[7];
    const float* cb11 = (const float*)d_in[8];
    const float* cw12 = (const float*)d_in[9];
    const float* cb12 = (const float*)d_in[10];
    const float* cpw1 = (const float*)d_in[11];
    const float* cpb1 = (const float*)d_in[12];
    const float* cw21 = (const float*)d_in[13];
    const float* cb21 = (const float*)d_in[14];
    const float* cw22 = (const float*)d_in[15];
    const float* cb22 = (const float*)d_in[16];
    const float* cpw2 = (const float*)d_in[17];
    const float* cpb2 = (const float*)d_in[18];
    const int* indices = (const int*)d_in[19];
    const int* table   = (const int*)d_in[20];
    const int M = in_sizes[0] / 16;   // 400000

    // workspace layout (bytes); total ~257.7 MB
    char* ws = (char*)d_ws;
    float* A   = (float*)(ws);                    // M x 64
    float* B   = (float*)(ws + 102400000ull);     // M x 64
    float* BEV = (float*)(ws + 204800000ull);     // 64 x 65536
    float* T1  = (float*)(ws + 221577216ull);     // 64 x 65536
    float* T2  = (float*)(ws + 238354432ull);     // 64 x 65536
    float* S1  = (float*)(ws + 255131648ull);     // 3 x 65536
    float* S2  = (float*)(ws + 255918080ull);     // 3 x 65536
    float* WT1 = (float*)(ws + 256704512ull);     // 27x64x16
    float* WT2 = (float*)(ws + 256815104ull);     // 27x64x64
    float* WT3 = (float*)(ws + 257257472ull);     // 27x64x64

    transpose_w_k<16><<<27, 256, 0, stream>>>(w1, WT1);
    transpose_w_k<64><<<27, 256, 0, stream>>>(w2, WT2);
    transpose_w_k<64><<<27, 256, 0, stream>>>(w3, WT3);

    int pblocks = (M + 3) / 4;
    subm_conv_k<16, true ><<<pblocks, 256, 0, stream>>>(features, indices, table, WT1, b1, A, M);
    subm_conv_k<64, true ><<<pblocks, 256, 0, stream>>>(A, indices, table, WT2, b2, B, M);
    subm_conv_k<64, false><<<pblocks, 256, 0, stream>>>(B, indices, table, WT3, b3, A, M);

    bev_max_k<<<NCELL / 4, 256, 0, stream>>>(A, table, BEV);

    conv5_k<64, 16, true ><<<dim3(16, 16, 4), 256, 0, stream>>>(BEV, cw11, cb11, T1);
    conv5_k<64, 16, false><<<dim3(16, 16, 4), 256, 0, stream>>>(T1, cw12, cb12, T2);
    pw_add_relu_k<<<dim3(NCELL / 256, 64), 256, 0, stream>>>(BEV, cpw1, cpb1, T2, T1);

    conv5_k<64, 3, true ><<<dim3(16, 16, 1), 256, 0, stream>>>(T1, cw21, cb21, S1);
    conv5_k<3, 3, false><<<dim3(16, 16, 1), 256, 0, stream>>>(S1, cw22, cb22, S2);
    pw_final_k<<<NCELL / 256, 256, 0, stream>>>(T1, cpw2, cpb2, S2, (float*)d_out);
}

// Round 2
// 1565.618 us; speedup vs baseline: 5.6038x; 5.6038x over previous
//
#include <hip/hip_runtime.h>
#include <math.h>

#define NXD 256
#define NYD 256
#define NZD 64
#define NCELL (NXD*NYD)

typedef __bf16 bf16x8 __attribute__((ext_vector_type(8)));
typedef float f32x4 __attribute__((ext_vector_type(4)));

// ---------------- f32 -> bf16 convert ----------------
__global__ __launch_bounds__(256) void f2bf_k(const float* __restrict__ in,
                                              __bf16* __restrict__ out, int n) {
    int i = blockIdx.x * 256 + threadIdx.x;
    if (i < n) out[i] = (__bf16)in[i];
}

// ------- weight transpose+cast: w(k, ci, co) f32 -> wt(k, co, ci[KPAD]) bf16 ----
template<int CIN, int KPAD>
__global__ __launch_bounds__(256) void transpose_w_bf_k(const float* __restrict__ w,
                                                        __bf16* __restrict__ wt) {
    int k = blockIdx.x;
    for (int idx = threadIdx.x; idx < 64 * KPAD; idx += 256) {
        int ci = idx % KPAD, co = idx / KPAD;
        float v = (ci < CIN) ? w[((size_t)k * CIN + ci) * 64 + co] : 0.f;
        wt[((size_t)k * 64 + co) * KPAD + ci] = (__bf16)v;
    }
}

// ---------------- submanifold sparse conv via MFMA ------------------------------
// block = 256 threads (4 waves) handles 64 points x 64 c_out.
// per offset k: gather neighbor feature rows -> LDS Nf[64][KPAD(+8)], stage
// W_k^T[co][ci] -> LDS Wt, then mfma_f32_16x16x32_bf16.
// wave wid owns c_out tile [wid*16, wid*16+16); acc[pt] covers points pt*16..+16.
template<int CIN, bool RELU, bool OUTF32>
__global__ __launch_bounds__(256) void subm_mfma_k(
        const __bf16* __restrict__ feats,      // M x CIN
        const int* __restrict__ indices,       // M x 4
        const int* __restrict__ table,
        const __bf16* __restrict__ wt,         // 27 x 64 x KPAD (padded, bf16)
        const float* __restrict__ bias,
        void* __restrict__ outv, int M) {
    constexpr int KPAD = (CIN < 32) ? 32 : CIN;
    constexpr int KS = KPAD / 32;              // K-steps of 32
    constexpr int LROW = KPAD + 8;             // +16B pad per row -> 2-way banks
    __shared__ __bf16 Nf[64 * LROW];
    __shared__ __bf16 Wt[64 * LROW];

    const int tid = threadIdx.x;
    const int p0 = blockIdx.x * 64;
    const int lane = tid & 63;
    const int wid  = tid >> 6;
    const int lr = lane & 15;                  // col within tiles
    const int lg = lane >> 4;                  // k-group / row-group

    // gather-role mapping
    int gp, gh;                                // point, chunk
    if (CIN == 64) { gp = tid & 63; gh = tid >> 6; }   // 32B chunks (16 bf16)
    else           { gp = tid >> 2; gh = tid & 3;  }   // 8B chunks (4 bf16)

    const int4 ind = ((const int4*)indices)[p0 + gp];
    const int px = ind.y, py = ind.z, pz = ind.w;

    f32x4 acc[4];
    {
        float b = bias[wid * 16 + lr];
        #pragma unroll
        for (int pt = 0; pt < 4; ++pt) acc[pt] = f32x4{b, b, b, b};
    }

    #pragma unroll 1
    for (int k = 0; k < 27; ++k) {
        const int dx = k / 9 - 1, dy = (k / 3) % 3 - 1, dz = k % 3 - 1;
        const int nx = px + dx, ny = py + dy, nz = pz + dz;
        const bool valid = (nx >= 0) & (nx < NXD) & (ny >= 0) & (ny < NYD) &
                           (nz >= 0) & (nz < NZD);
        int row = 0;
        if (valid) row = table[(nx * NYD + ny) * NZD + nz];

        uint4 fa = {0,0,0,0}, fb = {0,0,0,0};
        uint2 fs = {0,0};
        if (CIN == 64) {
            if (row > 0) {
                const uint4* src = (const uint4*)(feats + (size_t)(row - 1) * 64) + gh * 2;
                fa = src[0]; fb = src[1];
            }
        } else {
            if (row > 0)
                fs = ((const uint2*)(feats + (size_t)(row - 1) * 16))[gh];
        }
        // weight stage loads (L2-hot)
        uint4 wa, wb;
        if (CIN == 64) {
            const uint4* wsrc = (const uint4*)(wt + ((size_t)k * 64 + (tid >> 2)) * 64) + (tid & 3) * 2;
            wa = wsrc[0]; wb = wsrc[1];
        } else {
            wa = ((const uint4*)(wt + ((size_t)k * 64 + (tid >> 2)) * 32))[tid & 3];
        }

        __syncthreads();   // previous iteration's MFMA reads complete
        if (CIN == 64) {
            *(uint4*)&Nf[gp * LROW + gh * 16]     = fa;
            *(uint4*)&Nf[gp * LROW + gh * 16 + 8] = fb;
            *(uint4*)&Wt[(tid >> 2) * LROW + (tid & 3) * 16]     = wa;
            *(uint4*)&Wt[(tid >> 2) * LROW + (tid & 3) * 16 + 8] = wb;
        } else {
            *(uint2*)&Nf[gp * LROW + gh * 4]      = fs;
            *(uint2*)&Nf[gp * LROW + 16 + gh * 4] = uint2{0, 0};   // zero pad ci 16..31
            *(uint4*)&Wt[(tid >> 2) * LROW + (tid & 3) * 8] = wa;
        }
        __syncthreads();

        bf16x8 bfrag[KS];
        #pragma unroll
        for (int ks = 0; ks < KS; ++ks)
            bfrag[ks] = *(const bf16x8*)&Wt[(wid * 16 + lr) * LROW + ks * 32 + lg * 8];
        #pragma unroll
        for (int pt = 0; pt < 4; ++pt) {
            #pragma unroll
            for (int ks = 0; ks < KS; ++ks) {
                bf16x8 afrag = *(const bf16x8*)&Nf[(pt * 16 + lr) * LROW + ks * 32 + lg * 8];
                acc[pt] = __builtin_amdgcn_mfma_f32_16x16x32_bf16(afrag, bfrag[ks], acc[pt], 0, 0, 0);
            }
        }
    }

    // epilogue: C/D layout col=lane&15 (co), row=(lane>>4)*4+reg (point)
    #pragma unroll
    for (int pt = 0; pt < 4; ++pt) {
        #pragma unroll
        for (int r = 0; r < 4; ++r) {
            int p = p0 + pt * 16 + lg * 4 + r;
            int co = wid * 16 + lr;
            float v = acc[pt][r];
            if (RELU) v = fmaxf(v, 0.f);
            if (OUTF32) ((float*)outv)[(size_t)p * 64 + co] = v;
            else        ((__bf16*)outv)[(size_t)p * 64 + co] = (__bf16)v;
        }
    }
}

// ---------------- BEV segment max: one wave per (x,y) cell ----------------------
__global__ __launch_bounds__(256) void bev_max_k(const float* __restrict__ h,
        const int* __restrict__ table, float* __restrict__ bev) {
    int cell = blockIdx.x * 4 + (threadIdx.x >> 6);
    int lane = threadIdx.x & 63;
    int r = table[cell * 64 + lane];          // z = lane (NZ==64)
    float acc = -INFINITY;
    #pragma unroll 1
    for (int z = 0; z < 64; ++z) {
        int row = __shfl(r, z, 64);           // wave-uniform
        if (row > 0) acc = fmaxf(acc, h[(size_t)(row - 1) * 64 + lane]);
    }
    bev[(size_t)lane * NCELL + cell] = (acc == -INFINITY) ? 0.f : acc;
}

// ---------------- dense 5x5 conv, NCHW, pad 2; 16x16 tile per block -------------
template<int CIN, int COB, bool RELU>
__global__ __launch_bounds__(256) void conv5_k(const float* __restrict__ in,
        const float* __restrict__ w, const float* __restrict__ bias,
        float* __restrict__ out) {
    __shared__ float tile[20][20];
    int tid = threadIdx.x;
    int tx = tid & 15, ty = tid >> 4;
    int gx0 = blockIdx.x * 16 - 2, gy0 = blockIdx.y * 16 - 2;
    int co_base = blockIdx.z * COB;
    float acc[COB];
    #pragma unroll
    for (int i = 0; i < COB; ++i) acc[i] = bias[co_base + i];

    #pragma unroll 1
    for (int ci = 0; ci < CIN; ++ci) {
        __syncthreads();
        for (int idx = tid; idx < 400; idx += 256) {
            int r = idx / 20, cc = idx % 20;
            int sy = gy0 + r, sx = gx0 + cc;
            float v = 0.f;
            if (sy >= 0 && sy < NXD && sx >= 0 && sx < NYD)
                v = in[(size_t)ci * NCELL + sy * NYD + sx];
            tile[r][cc] = v;
        }
        __syncthreads();
        const float* wrow = w + ((size_t)co_base * CIN + ci) * 25;
        #pragma unroll
        for (int dy = 0; dy < 5; ++dy)
        #pragma unroll
        for (int dx = 0; dx < 5; ++dx) {
            float iv = tile[ty + dy][tx + dx];
            #pragma unroll
            for (int co = 0; co < COB; ++co)
                acc[co] = fmaf(iv, wrow[(size_t)co * CIN * 25 + dy * 5 + dx], acc[co]);
        }
    }
    int gy = gy0 + 2 + ty, gx = gx0 + 2 + tx;
    #pragma unroll
    for (int co = 0; co < COB; ++co) {
        float v = acc[co];
        if (RELU) v = fmaxf(v, 0.f);
        out[(size_t)(co_base + co) * NCELL + gy * NYD + gx] = v;
    }
}

// ---------------- pointwise 64->64 + residual add + relu ------------------------
__global__ __launch_bounds__(256) void pw_add_relu_k(const float* __restrict__ x,
        const float* __restrict__ pw, const float* __restrict__ pb,
        const float* __restrict__ h2, float* __restrict__ out) {
    int pix = blockIdx.x * 256 + threadIdx.x;
    int co = blockIdx.y;
    float acc = pb[co] + h2[(size_t)co * NCELL + pix];
    const float* wr = pw + (size_t)co * 64;
    #pragma unroll 8
    for (int ci = 0; ci < 64; ++ci)
        acc = fmaf(x[(size_t)ci * NCELL + pix], wr[ci], acc);
    out[(size_t)co * NCELL + pix] = fmaxf(acc, 0.f);
}

// ---------------- final pointwise 64->3 + residual + relu + NHWC write ----------
__global__ __launch_bounds__(256) void pw_final_k(const float* __restrict__ x,
        const float* __restrict__ pw, const float* __restrict__ pb,
        const float* __restrict__ h2, float* __restrict__ out) {
    int pix = blockIdx.x * 256 + threadIdx.x;
    float acc[3];
    #pragma unroll
    for (int co = 0; co < 3; ++co) acc[co] = pb[co] + h2[(size_t)co * NCELL + pix];
    #pragma unroll 4
    for (int ci = 0; ci < 64; ++ci) {
        float v = x[(size_t)ci * NCELL + pix];
        #pragma unroll
        for (int co = 0; co < 3; ++co) acc[co] = fmaf(v, pw[co * 64 + ci], acc[co]);
    }
    #pragma unroll
    for (int co = 0; co < 3; ++co) out[(size_t)pix * 3 + co] = fmaxf(acc[co], 0.f);
}

extern "C" void kernel_launch(void* const* d_in, const int* in_sizes, int n_in,
                              void* d_out, int out_size, void* d_ws, size_t ws_size,
                              hipStream_t stream) {
    const float* features = (const float*)d_in[0];
    const float* w1   = (const float*)d_in[1];
    const float* b1   = (const float*)d_in[2];
    const float* w2   = (const float*)d_in[3];
    const float* b2   = (const float*)d_in[4];
    const float* w3   = (const float*)d_in[5];
    const float* b3   = (const float*)d_in[6];
    const float* cw11 = (const float*)d_in[7];
    const float* cb11 = (const float*)d_in[8];
    const float* cw12 = (const float*)d_in[9];
    const float* cb12 = (const float*)d_in[10];
    const float* cpw1 = (const float*)d_in[11];
    const float* cpb1 = (const float*)d_in[12];
    const float* cw21 = (const float*)d_in[13];
    const float* cb21 = (const float*)d_in[14];
    const float* cw22 = (const float*)d_in[15];
    const float* cb22 = (const float*)d_in[16];
    const float* cpw2 = (const float*)d_in[17];
    const float* cpb2 = (const float*)d_in[18];
    const int* indices = (const int*)d_in[19];
    const int* table   = (const int*)d_in[20];
    const int M = in_sizes[0] / 16;   // 400000  (divisible by 64)

    // workspace layout (bytes), total 257,257,472
    char* ws = (char*)d_ws;
    __bf16* A_bf   = (__bf16*)(ws);                     // M x 64 bf16 (layer1 out)
    __bf16* B_bf   = (__bf16*)(ws +  51200000ull);      // M x 64 bf16 (layer2 out)
    __bf16* feat_bf= (__bf16*)(ws + 102400000ull);      // M x 16 bf16 (dead after L1)
    float*  C      = (float*) (ws + 102400000ull);      // M x 64 f32  (layer3 out, overlaps feat_bf)
    float*  BEV    = (float*) (ws + 204800000ull);      // 64 x 65536
    float*  T1     = (float*) (ws + 221577216ull);
    float*  T2     = (float*) (ws + 238354432ull);
    float*  S1     = (float*) (ws + 255131648ull);
    float*  S2     = (float*) (ws + 255918080ull);
    __bf16* WT1    = (__bf16*)(ws + 256704512ull);      // 27x64x32 bf16
    __bf16* WT2    = (__bf16*)(ws + 256815104ull);      // 27x64x64 bf16
    __bf16* WT3    = (__bf16*)(ws + 257036288ull);      // 27x64x64 bf16

    f2bf_k<<<(M * 16 + 255) / 256, 256, 0, stream>>>(features, feat_bf, M * 16);
    transpose_w_bf_k<16, 32><<<27, 256, 0, stream>>>(w1, WT1);
    transpose_w_bf_k<64, 64><<<27, 256, 0, stream>>>(w2, WT2);
    transpose_w_bf_k<64, 64><<<27, 256, 0, stream>>>(w3, WT3);

    const int pblocks = M / 64;  // 6250
    subm_mfma_k<16, true,  false><<<pblocks, 256, 0, stream>>>(feat_bf, indices, table, WT1, b1, A_bf, M);
    subm_mfma_k<64, true,  false><<<pblocks, 256, 0, stream>>>(A_bf,    indices, table, WT2, b2, B_bf, M);
    subm_mfma_k<64, false, true ><<<pblocks, 256, 0, stream>>>(B_bf,    indices, table, WT3, b3, C,    M);

    bev_max_k<<<NCELL / 4, 256, 0, stream>>>(C, table, BEV);

    conv5_k<64, 16, true ><<<dim3(16, 16, 4), 256, 0, stream>>>(BEV, cw11, cb11, T1);
    conv5_k<64, 16, false><<<dim3(16, 16, 4), 256, 0, stream>>>(T1, cw12, cb12, T2);
    pw_add_relu_k<<<dim3(NCELL / 256, 64), 256, 0, stream>>>(BEV, cpw1, cpb1, T2, T1);

    conv5_k<64, 3, true ><<<dim3(16, 16, 1), 256, 0, stream>>>(T1, cw21, cb21, S1);
    conv5_k<3, 3, false><<<dim3(16, 16, 1), 256, 0, stream>>>(S1, cw22, cb22, S2);
    pw_final_k<<<NCELL / 256, 256, 0, stream>>>(T1, cpw2, cpb2, S2, (float*)d_out);
}

// Round 3
// 693.486 us; speedup vs baseline: 12.6512x; 2.2576x over previous
//
#include <hip/hip_runtime.h>
#include <math.h>

#define NXD 256
#define NYD 256
#define NZD 64
#define NCELL (NXD*NYD)

typedef __bf16 bf16x8 __attribute__((ext_vector_type(8)));
typedef float f32x4 __attribute__((ext_vector_type(4)));

// ---------------- f32 -> bf16 convert ----------------
__global__ __launch_bounds__(256) void f2bf_k(const float* __restrict__ in,
                                              __bf16* __restrict__ out, int n) {
    int i = blockIdx.x * 256 + threadIdx.x;
    if (i < n) out[i] = (__bf16)in[i];
}

// ------- weight transpose+cast: w(k, ci, co) f32 -> wt(k, co, ci[KPAD]) bf16 ----
template<int CIN, int KPAD>
__global__ __launch_bounds__(256) void transpose_w_bf_k(const float* __restrict__ w,
                                                        __bf16* __restrict__ wt) {
    int k = blockIdx.x;
    for (int idx = threadIdx.x; idx < 64 * KPAD; idx += 256) {
        int ci = idx % KPAD, co = idx / KPAD;
        float v = (ci < CIN) ? w[((size_t)k * CIN + ci) * 64 + co] : 0.f;
        wt[((size_t)k * 64 + co) * KPAD + ci] = (__bf16)v;
    }
}

// ------- conv weight transpose: OIHW (CO,64,5,5) f32 -> wt[k25][COPAD][64] bf16 -
template<int CO, int COPAD>
__global__ __launch_bounds__(256) void transpose_cw_k(const float* __restrict__ w,
                                                      __bf16* __restrict__ wt) {
    int k = blockIdx.x;  // 0..24
    for (int idx = threadIdx.x; idx < COPAD * 64; idx += 256) {
        int ci = idx & 63, co = idx >> 6;
        float v = (co < CO) ? w[((size_t)co * 64 + ci) * 25 + k] : 0.f;
        wt[((size_t)k * COPAD + co) * 64 + ci] = (__bf16)v;
    }
}

// ---------------- submanifold sparse conv via MFMA ------------------------------
template<int CIN, bool RELU, bool OUTF32>
__global__ __launch_bounds__(256) void subm_mfma_k(
        const __bf16* __restrict__ feats,      // M x CIN
        const int* __restrict__ indices,       // M x 4
        const int* __restrict__ table,
        const __bf16* __restrict__ wt,         // 27 x 64 x KPAD (padded, bf16)
        const float* __restrict__ bias,
        void* __restrict__ outv, int M) {
    constexpr int KPAD = (CIN < 32) ? 32 : CIN;
    constexpr int KS = KPAD / 32;              // K-steps of 32
    constexpr int LROW = KPAD + 8;             // +16B pad per row -> 2-way banks
    __shared__ __bf16 Nf[64 * LROW];
    __shared__ __bf16 Wt[64 * LROW];

    const int tid = threadIdx.x;
    const int p0 = blockIdx.x * 64;
    const int lane = tid & 63;
    const int wid  = tid >> 6;
    const int lr = lane & 15;
    const int lg = lane >> 4;

    int gp, gh;
    if (CIN == 64) { gp = tid & 63; gh = tid >> 6; }
    else           { gp = tid >> 2; gh = tid & 3;  }

    const int4 ind = ((const int4*)indices)[p0 + gp];
    const int px = ind.y, py = ind.z, pz = ind.w;

    f32x4 acc[4];
    {
        float b = bias[wid * 16 + lr];
        #pragma unroll
        for (int pt = 0; pt < 4; ++pt) acc[pt] = f32x4{b, b, b, b};
    }

    #pragma unroll 1
    for (int k = 0; k < 27; ++k) {
        const int dx = k / 9 - 1, dy = (k / 3) % 3 - 1, dz = k % 3 - 1;
        const int nx = px + dx, ny = py + dy, nz = pz + dz;
        const bool valid = (nx >= 0) & (nx < NXD) & (ny >= 0) & (ny < NYD) &
                           (nz >= 0) & (nz < NZD);
        int row = 0;
        if (valid) row = table[(nx * NYD + ny) * NZD + nz];

        uint4 fa = {0,0,0,0}, fb = {0,0,0,0};
        uint2 fs = {0,0};
        if (CIN == 64) {
            if (row > 0) {
                const uint4* src = (const uint4*)(feats + (size_t)(row - 1) * 64) + gh * 2;
                fa = src[0]; fb = src[1];
            }
        } else {
            if (row > 0)
                fs = ((const uint2*)(feats + (size_t)(row - 1) * 16))[gh];
        }
        uint4 wa, wb;
        if (CIN == 64) {
            const uint4* wsrc = (const uint4*)(wt + ((size_t)k * 64 + (tid >> 2)) * 64) + (tid & 3) * 2;
            wa = wsrc[0]; wb = wsrc[1];
        } else {
            wa = ((const uint4*)(wt + ((size_t)k * 64 + (tid >> 2)) * 32))[tid & 3];
        }

        __syncthreads();
        if (CIN == 64) {
            *(uint4*)&Nf[gp * LROW + gh * 16]     = fa;
            *(uint4*)&Nf[gp * LROW + gh * 16 + 8] = fb;
            *(uint4*)&Wt[(tid >> 2) * LROW + (tid & 3) * 16]     = wa;
            *(uint4*)&Wt[(tid >> 2) * LROW + (tid & 3) * 16 + 8] = wb;
        } else {
            *(uint2*)&Nf[gp * LROW + gh * 4]      = fs;
            *(uint2*)&Nf[gp * LROW + 16 + gh * 4] = uint2{0, 0};
            *(uint4*)&Wt[(tid >> 2) * LROW + (tid & 3) * 8] = wa;
        }
        __syncthreads();

        bf16x8 bfrag[KS];
        #pragma unroll
        for (int ks = 0; ks < KS; ++ks)
            bfrag[ks] = *(const bf16x8*)&Wt[(wid * 16 + lr) * LROW + ks * 32 + lg * 8];
        #pragma unroll
        for (int pt = 0; pt < 4; ++pt) {
            #pragma unroll
            for (int ks = 0; ks < KS; ++ks) {
                bf16x8 afrag = *(const bf16x8*)&Nf[(pt * 16 + lr) * LROW + ks * 32 + lg * 8];
                acc[pt] = __builtin_amdgcn_mfma_f32_16x16x32_bf16(afrag, bfrag[ks], acc[pt], 0, 0, 0);
            }
        }
    }

    #pragma unroll
    for (int pt = 0; pt < 4; ++pt) {
        #pragma unroll
        for (int r = 0; r < 4; ++r) {
            int p = p0 + pt * 16 + lg * 4 + r;
            int co = wid * 16 + lr;
            float v = acc[pt][r];
            if (RELU) v = fmaxf(v, 0.f);
            if (OUTF32) ((float*)outv)[(size_t)p * 64 + co] = v;
            else        ((__bf16*)outv)[(size_t)p * 64 + co] = (__bf16)v;
        }
    }
}

// ---------------- BEV segment max -> bf16 NHWC ----------------------------------
__global__ __launch_bounds__(256) void bev_max_k(const float* __restrict__ h,
        const int* __restrict__ table, __bf16* __restrict__ bev) {
    int cell = blockIdx.x * 4 + (threadIdx.x >> 6);
    int lane = threadIdx.x & 63;
    int r = table[cell * 64 + lane];          // z = lane (NZ==64)
    float acc = -INFINITY;
    #pragma unroll 1
    for (int z = 0; z < 64; ++z) {
        int row = __shfl(r, z, 64);           // wave-uniform
        if (row > 0) acc = fmaxf(acc, h[(size_t)(row - 1) * 64 + lane]);
    }
    bev[(size_t)cell * 64 + lane] = (__bf16)((acc == -INFINITY) ? 0.f : acc);
}

// ---------------- dense 5x5 conv via MFMA, NHWC bf16 in/out ---------------------
// block: 16x16 pixel tile x 64 co, 4 waves. Halo 20x20x64 bf16 staged once in
// LDS (XOR-swizzled 16B chunks), then 25 taps of mfma_f32_16x16x32_bf16.
// FUSE_PW: adds 1x1 conv on xres (residual branch) as a 26th tap.
template<bool RELU, bool FUSE_PW>
__global__ __launch_bounds__(256) void conv5_mfma_k(
        const __bf16* __restrict__ in,     // NHWC [NCELL][64]
        const __bf16* __restrict__ wtc,    // [25][64][64]
        const float* __restrict__ bias,    // [64]
        const __bf16* __restrict__ xres,   // NHWC (residual input, FUSE_PW)
        const __bf16* __restrict__ wpw,    // [64][64]
        const float* __restrict__ bpw,     // [64]
        __bf16* __restrict__ out) {        // NHWC
    __shared__ __bf16 halo[400 * 64];      // 51.2 KB
    __shared__ __bf16 xt[256 * 64];        // 32 KB (used when FUSE_PW)

    const int tid = threadIdx.x;
    const int gx0 = (blockIdx.x & 15) * 16;
    const int gy0 = (blockIdx.x >> 4) * 16;

    // stage halo (20x20 rows of 64 ci, 8 chunks of 16B each, XOR swizzle)
    for (int i = tid; i < 3200; i += 256) {
        int hp = i >> 3, ch = i & 7;
        int hy = hp / 20, hx = hp - hy * 20;
        int gy = gy0 - 2 + hy, gx = gx0 - 2 + hx;
        uint4 v = {0, 0, 0, 0};
        if (gy >= 0 && gy < NXD && gx >= 0 && gx < NYD)
            v = *(const uint4*)(in + (((size_t)(gy << 8) + gx) << 6) + ch * 8);
        *(uint4*)((char*)halo + hp * 128 + ((ch ^ (hp & 7)) << 4)) = v;
    }
    if (FUSE_PW) {
        for (int i = tid; i < 2048; i += 256) {
            int p = i >> 3, ch = i & 7;
            int gy = gy0 + (p >> 4), gx = gx0 + (p & 15);
            uint4 v = *(const uint4*)(xres + (((size_t)(gy << 8) + gx) << 6) + ch * 8);
            *(uint4*)((char*)xt + p * 128 + ((ch ^ (p & 7)) << 4)) = v;
        }
    }
    __syncthreads();

    const int lane = tid & 63, wid = tid >> 6;
    const int lr = lane & 15, lg = lane >> 4;
    const int co = wid * 16 + lr;

    f32x4 acc[16];
    {
        float b = bias[co] + (FUSE_PW ? bpw[co] : 0.f);
        #pragma unroll
        for (int pt = 0; pt < 16; ++pt) acc[pt] = f32x4{b, b, b, b};
    }

    #pragma unroll 1
    for (int k = 0; k < 25; ++k) {
        const int dy = k / 5, dx = k - dy * 5;
        const __bf16* wrow = wtc + ((size_t)k * 64 + co) * 64 + lg * 8;
        bf16x8 bf0 = *(const bf16x8*)wrow;
        bf16x8 bf1 = *(const bf16x8*)(wrow + 32);
        #pragma unroll
        for (int pt = 0; pt < 16; ++pt) {
            int hp = (pt + dy) * 20 + lr + dx;
            bf16x8 a0 = *(const bf16x8*)((char*)halo + hp * 128 + ((lg ^ (hp & 7)) << 4));
            bf16x8 a1 = *(const bf16x8*)((char*)halo + hp * 128 + (((4 + lg) ^ (hp & 7)) << 4));
            acc[pt] = __builtin_amdgcn_mfma_f32_16x16x32_bf16(a0, bf0, acc[pt], 0, 0, 0);
            acc[pt] = __builtin_amdgcn_mfma_f32_16x16x32_bf16(a1, bf1, acc[pt], 0, 0, 0);
        }
    }
    if (FUSE_PW) {
        const __bf16* wrow = wpw + (size_t)co * 64 + lg * 8;
        bf16x8 bf0 = *(const bf16x8*)wrow;
        bf16x8 bf1 = *(const bf16x8*)(wrow + 32);
        #pragma unroll
        for (int pt = 0; pt < 16; ++pt) {
            int p = pt * 16 + lr;
            bf16x8 a0 = *(const bf16x8*)((char*)xt + p * 128 + ((lg ^ (p & 7)) << 4));
            bf16x8 a1 = *(const bf16x8*)((char*)xt + p * 128 + (((4 + lg) ^ (p & 7)) << 4));
            acc[pt] = __builtin_amdgcn_mfma_f32_16x16x32_bf16(a0, bf0, acc[pt], 0, 0, 0);
            acc[pt] = __builtin_amdgcn_mfma_f32_16x16x32_bf16(a1, bf1, acc[pt], 0, 0, 0);
        }
    }

    // C/D: col(lane&15)=co-row of B, row=(lane>>4)*4+reg = pixel row of A
    #pragma unroll
    for (int pt = 0; pt < 16; ++pt) {
        int gy = gy0 + pt;
        #pragma unroll
        for (int r = 0; r < 4; ++r) {
            int gx = gx0 + lg * 4 + r;
            float v = acc[pt][r];
            if (RELU) v = fmaxf(v, 0.f);
            out[(((size_t)(gy << 8) + gx) << 6) + co] = (__bf16)v;
        }
    }
}

// ---------------- dense 5x5 conv 64 -> 3 (co padded to 16), f32 planar out ------
__global__ __launch_bounds__(256) void conv5_mfma3_k(
        const __bf16* __restrict__ in,     // NHWC [NCELL][64]
        const __bf16* __restrict__ wtc,    // [25][16][64] (co padded)
        const float* __restrict__ bias3,   // [3]
        float* __restrict__ out) {         // planar [3][NCELL]
    __shared__ __bf16 halo[400 * 64];

    const int tid = threadIdx.x;
    const int gx0 = (blockIdx.x & 15) * 16;
    const int gy0 = (blockIdx.x >> 4) * 16;

    for (int i = tid; i < 3200; i += 256) {
        int hp = i >> 3, ch = i & 7;
        int hy = hp / 20, hx = hp - hy * 20;
        int gy = gy0 - 2 + hy, gx = gx0 - 2 + hx;
        uint4 v = {0, 0, 0, 0};
        if (gy >= 0 && gy < NXD && gx >= 0 && gx < NYD)
            v = *(const uint4*)(in + (((size_t)(gy << 8) + gx) << 6) + ch * 8);
        *(uint4*)((char*)halo + hp * 128 + ((ch ^ (hp & 7)) << 4)) = v;
    }
    __syncthreads();

    const int lane = tid & 63, wid = tid >> 6;
    const int lr = lane & 15, lg = lane >> 4;

    f32x4 acc[4];
    {
        float b = (lr < 3) ? bias3[lr] : 0.f;
        #pragma unroll
        for (int t = 0; t < 4; ++t) acc[t] = f32x4{b, b, b, b};
    }

    #pragma unroll 1
    for (int k = 0; k < 25; ++k) {
        const int dy = k / 5, dx = k - dy * 5;
        const __bf16* wrow = wtc + ((size_t)k * 16 + lr) * 64 + lg * 8;
        bf16x8 bf0 = *(const bf16x8*)wrow;
        bf16x8 bf1 = *(const bf16x8*)(wrow + 32);
        #pragma unroll
        for (int t = 0; t < 4; ++t) {
            int pt = wid * 4 + t;
            int hp = (pt + dy) * 20 + lr + dx;
            bf16x8 a0 = *(const bf16x8*)((char*)halo + hp * 128 + ((lg ^ (hp & 7)) << 4));
            bf16x8 a1 = *(const bf16x8*)((char*)halo + hp * 128 + (((4 + lg) ^ (hp & 7)) << 4));
            acc[t] = __builtin_amdgcn_mfma_f32_16x16x32_bf16(a0, bf0, acc[t], 0, 0, 0);
            acc[t] = __builtin_amdgcn_mfma_f32_16x16x32_bf16(a1, bf1, acc[t], 0, 0, 0);
        }
    }

    if (lr < 3) {
        #pragma unroll
        for (int t = 0; t < 4; ++t) {
            int gy = gy0 + wid * 4 + t;
            #pragma unroll
            for (int r = 0; r < 4; ++r) {
                int gx = gx0 + lg * 4 + r;
                out[(size_t)lr * NCELL + (gy << 8) + gx] = fmaxf(acc[t][r], 0.f);
            }
        }
    }
}

// ---------------- dense 5x5 conv, scalar (3->3 only), f32 planar ----------------
template<int CIN, int COB, bool RELU>
__global__ __launch_bounds__(256) void conv5_k(const float* __restrict__ in,
        const float* __restrict__ w, const float* __restrict__ bias,
        float* __restrict__ out) {
    __shared__ float tile[20][20];
    int tid = threadIdx.x;
    int tx = tid & 15, ty = tid >> 4;
    int gx0 = blockIdx.x * 16 - 2, gy0 = blockIdx.y * 16 - 2;
    int co_base = blockIdx.z * COB;
    float acc[COB];
    #pragma unroll
    for (int i = 0; i < COB; ++i) acc[i] = bias[co_base + i];

    #pragma unroll 1
    for (int ci = 0; ci < CIN; ++ci) {
        __syncthreads();
        for (int idx = tid; idx < 400; idx += 256) {
            int r = idx / 20, cc = idx % 20;
            int sy = gy0 + r, sx = gx0 + cc;
            float v = 0.f;
            if (sy >= 0 && sy < NXD && sx >= 0 && sx < NYD)
                v = in[(size_t)ci * NCELL + sy * NYD + sx];
            tile[r][cc] = v;
        }
        __syncthreads();
        const float* wrow = w + ((size_t)co_base * CIN + ci) * 25;
        #pragma unroll
        for (int dy = 0; dy < 5; ++dy)
        #pragma unroll
        for (int dx = 0; dx < 5; ++dx) {
            float iv = tile[ty + dy][tx + dx];
            #pragma unroll
            for (int co = 0; co < COB; ++co)
                acc[co] = fmaf(iv, wrow[(size_t)co * CIN * 25 + dy * 5 + dx], acc[co]);
        }
    }
    int gy = gy0 + 2 + ty, gx = gx0 + 2 + tx;
    #pragma unroll
    for (int co = 0; co < COB; ++co) {
        float v = acc[co];
        if (RELU) v = fmaxf(v, 0.f);
        out[(size_t)(co_base + co) * NCELL + gy * NYD + gx] = v;
    }
}

// ---------------- final pointwise 64->3 + residual + relu + NHWC write ----------
__global__ __launch_bounds__(256) void pw_final_k(const __bf16* __restrict__ x,
        const float* __restrict__ pw, const float* __restrict__ pb,
        const float* __restrict__ h2, float* __restrict__ out) {
    int pix = blockIdx.x * 256 + threadIdx.x;
    float acc[3];
    #pragma unroll
    for (int co = 0; co < 3; ++co) acc[co] = pb[co] + h2[(size_t)co * NCELL + pix];
    const bf16x8* xr = (const bf16x8*)(x + (size_t)pix * 64);
    #pragma unroll
    for (int j = 0; j < 8; ++j) {
        bf16x8 v8 = xr[j];
        #pragma unroll
        for (int e = 0; e < 8; ++e) {
            float v = (float)v8[e];
            int ci = j * 8 + e;
            #pragma unroll
            for (int co = 0; co < 3; ++co) acc[co] = fmaf(v, pw[co * 64 + ci], acc[co]);
        }
    }
    #pragma unroll
    for (int co = 0; co < 3; ++co) out[(size_t)pix * 3 + co] = fmaxf(acc[co], 0.f);
}

extern "C" void kernel_launch(void* const* d_in, const int* in_sizes, int n_in,
                              void* d_out, int out_size, void* d_ws, size_t ws_size,
                              hipStream_t stream) {
    const float* features = (const float*)d_in[0];
    const float* w1   = (const float*)d_in[1];
    const float* b1   = (const float*)d_in[2];
    const float* w2   = (const float*)d_in[3];
    const float* b2   = (const float*)d_in[4];
    const float* w3   = (const float*)d_in[5];
    const float* b3   = (const float*)d_in[6];
    const float* cw11 = (const float*)d_in[7];
    const float* cb11 = (const float*)d_in[8];
    const float* cw12 = (const float*)d_in[9];
    const float* cb12 = (const float*)d_in[10];
    const float* cpw1 = (const float*)d_in[11];
    const float* cpb1 = (const float*)d_in[12];
    const float* cw21 = (const float*)d_in[13];
    const float* cb21 = (const float*)d_in[14];
    const float* cw22 = (const float*)d_in[15];
    const float* cb22 = (const float*)d_in[16];
    const float* cpw2 = (const float*)d_in[17];
    const float* cpb2 = (const float*)d_in[18];
    const int* indices = (const int*)d_in[19];
    const int* table   = (const int*)d_in[20];
    const int M = in_sizes[0] / 16;   // 400000  (divisible by 64)

    // workspace layout (bytes), total ~233 MB
    char* ws = (char*)d_ws;
    __bf16* A_bf    = (__bf16*)(ws);                    // M x 64 bf16
    __bf16* B_bf    = (__bf16*)(ws +  51200000ull);     // M x 64 bf16
    __bf16* feat_bf = (__bf16*)(ws + 102400000ull);     // M x 16 bf16 (dead after L1)
    float*  C       = (float*) (ws + 102400000ull);     // M x 64 f32 (overlaps feat_bf)
    __bf16* BEV     = (__bf16*)(ws + 204800000ull);     // [NCELL][64] bf16
    __bf16* H1      = (__bf16*)(ws + 213188608ull);     // [NCELL][64] bf16
    __bf16* T1      = (__bf16*)(ws + 221577216ull);     // [NCELL][64] bf16
    float*  S1      = (float*) (ws + 229965824ull);     // [3][NCELL]
    float*  S2      = (float*) (ws + 230752256ull);     // [3][NCELL]
    __bf16* WT1     = (__bf16*)(ws + 231538688ull);     // 27x64x32
    __bf16* WT2     = (__bf16*)(ws + 231649280ull);     // 27x64x64
    __bf16* WT3     = (__bf16*)(ws + 232091648ull);     // 27x64x64
    __bf16* WTC11   = (__bf16*)(ws + 232534016ull);     // 25x64x64
    __bf16* WTC12   = (__bf16*)(ws + 232738816ull);     // 25x64x64
    __bf16* WTC21   = (__bf16*)(ws + 232943616ull);     // 25x16x64
    __bf16* WPW1    = (__bf16*)(ws + 232994816ull);     // 64x64

    f2bf_k<<<(M * 16 + 255) / 256, 256, 0, stream>>>(features, feat_bf, M * 16);
    f2bf_k<<<16, 256, 0, stream>>>(cpw1, WPW1, 4096);
    transpose_w_bf_k<16, 32><<<27, 256, 0, stream>>>(w1, WT1);
    transpose_w_bf_k<64, 64><<<27, 256, 0, stream>>>(w2, WT2);
    transpose_w_bf_k<64, 64><<<27, 256, 0, stream>>>(w3, WT3);
    transpose_cw_k<64, 64><<<25, 256, 0, stream>>>(cw11, WTC11);
    transpose_cw_k<64, 64><<<25, 256, 0, stream>>>(cw12, WTC12);
    transpose_cw_k<3, 16><<<25, 256, 0, stream>>>(cw21, WTC21);

    const int pblocks = M / 64;  // 6250
    subm_mfma_k<16, true,  false><<<pblocks, 256, 0, stream>>>(feat_bf, indices, table, WT1, b1, A_bf, M);
    subm_mfma_k<64, true,  false><<<pblocks, 256, 0, stream>>>(A_bf,    indices, table, WT2, b2, B_bf, M);
    subm_mfma_k<64, false, true ><<<pblocks, 256, 0, stream>>>(B_bf,    indices, table, WT3, b3, C,    M);

    bev_max_k<<<NCELL / 4, 256, 0, stream>>>(C, table, BEV);

    // resblock 1 (64ch): conv11 -> H1; conv12 + fused pw/residual -> T1
    conv5_mfma_k<true, false><<<256, 256, 0, stream>>>(BEV, WTC11, cb11, nullptr, nullptr, nullptr, H1);
    conv5_mfma_k<true, true ><<<256, 256, 0, stream>>>(H1, WTC12, cb12, BEV, WPW1, cpb1, T1);

    // resblock 2 (3ch): conv21 (relu) -> S1; conv22 3->3 -> S2; final pw+res+relu
    conv5_mfma3_k<<<256, 256, 0, stream>>>(T1, WTC21, cb21, S1);
    conv5_k<3, 3, false><<<dim3(16, 16, 1), 256, 0, stream>>>(S1, cw22, cb22, S2);
    pw_final_k<<<NCELL / 256, 256, 0, stream>>>(T1, cpw2, cpb2, S2, (float*)d_out);
}